// Round 1
// baseline (103.810 us; speedup 1.0000x reference)
//
#include <hip/hip_runtime.h>

// ExactWeightedDTM: B=4, C=1, H=W=64, N=4096, M0=0.01, R=2.0.
// Since R=2, dists_pow == d2 (integer squared Euclidean distance, up to fp
// rounding ~1e-7 rel — negligible vs 9.9e-2 abs threshold). The reference's
// sort+cumsum+clamp reduces to: accumulate weights over pixels in increasing
// d2 until m_target = 0.01*total_mass; crossing group at distance T
// contributes (m_target - mass_below)*T. Tie groups are order-independent.
//
// Strategy: one fused kernel. Each 256-thread block stages its batch's whole
// 64x64 image into LDS (16 KB), block-reduces total_mass, then each thread
// (one output pixel) finds T via geometric expansion + integer binary search
// on t using clipped-disk mass scans F(t) = sum_{d2<=t} w, then one final
// strict-below scan for the weighted sum.

#define NPIX 4096

static __device__ __forceinline__ int imax(int a, int b) { return a > b ? a : b; }
static __device__ __forceinline__ int imin(int a, int b) { return a < b ? a : b; }

// floor(sqrt(v)) for v >= 0, exact via guard loops
static __device__ __forceinline__ int isqrt_le(int v) {
    int r = (int)sqrtf((float)v);
    while ((r + 1) * (r + 1) <= v) r++;
    while (r > 0 && r * r > v) r--;
    return r;
}

// F(t) = sum of weights over pixels with squared distance <= t (clipped disk)
static __device__ float mass_le(const float* __restrict__ img, int py, int px, int t) {
    float s = 0.f;
    const int r = isqrt_le(t);
    const int y0 = imax(py - r, 0), y1 = imin(py + r, 63);
    for (int y = y0; y <= y1; y++) {
        const int dy = y - py;
        const int rem = t - dy * dy;
        const int rx = isqrt_le(rem);
        const int x0 = imax(px - rx, 0), x1 = imin(px + rx, 63);
        const float* row = img + (y << 6);
        for (int x = x0; x <= x1; x++) s += row[x];
    }
    return s;
}

__global__ __launch_bounds__(256) void dtm_kernel(const float* __restrict__ images,
                                                  float* __restrict__ out) {
    __shared__ float img[NPIX];
    __shared__ float red[256];

    const int tid = threadIdx.x;
    const int gid = blockIdx.x * 256 + tid;
    const int b   = gid >> 12;          // 4096 pixels per batch, 16 blocks/batch
    const int pix = gid & (NPIX - 1);
    const int py  = pix >> 6;
    const int px  = pix & 63;

    // Stage this batch's image into LDS with float4 loads; fold in partial sum.
    const float4* src = (const float4*)(images + b * NPIX);
    float4* dst = (float4*)img;
    float partial = 0.f;
#pragma unroll
    for (int i = 0; i < 4; i++) {
        float4 v = src[tid + 256 * i];
        dst[tid + 256 * i] = v;
        partial += v.x + v.y + v.z + v.w;
    }
    red[tid] = partial;
    __syncthreads();
    for (int s = 128; s > 0; s >>= 1) {
        if (tid < s) red[tid] += red[tid + s];
        __syncthreads();
    }
    const float total    = red[0];
    const float m_target = 0.01f * total;

    float ans = 0.f;
    if (total > 0.f && m_target > 0.f) {
        // Phase 1: geometric expansion to bracket T.
        int lo = -1, hi = 8;
        float Fhi = mass_le(img, py, px, hi);
        while (Fhi < m_target && hi < 7938) {
            lo = hi;
            hi = imin(hi * 4, 7938);
            Fhi = mass_le(img, py, px, hi);
        }
        // Phase 2: binary search min t in (lo, hi] with F(t) >= m_target.
        while (hi - lo > 1) {
            const int mid = lo + ((hi - lo) >> 1);
            const float Fm = mass_le(img, py, px, mid);
            if (Fm >= m_target) hi = mid; else lo = mid;
        }
        const int T = hi;

        // Phase 3: strict-below scan for mass_{<T} and sum w*d2 over d2 < T.
        float mass_lt = 0.f, wd = 0.f;
        const int tm1 = T - 1;
        if (tm1 >= 0) {
            const int r = isqrt_le(tm1);
            const int y0 = imax(py - r, 0), y1 = imin(py + r, 63);
            for (int y = y0; y <= y1; y++) {
                const int dy  = y - py;
                const int dy2 = dy * dy;
                const int rem = tm1 - dy2;
                if (rem < 0) continue;
                const int rx = isqrt_le(rem);
                const int x0 = imax(px - rx, 0), x1 = imin(px + rx, 63);
                const float* row = img + (y << 6);
                for (int x = x0; x <= x1; x++) {
                    const int dx = x - px;
                    const float wv = row[x];
                    mass_lt += wv;
                    wd += wv * (float)(dy2 + dx * dx);
                }
            }
        }
        float rem_mass = m_target - mass_lt;
        if (rem_mass < 0.f) rem_mass = 0.f;
        const float wsum = wd + rem_mass * (float)T;
        ans = sqrtf(wsum / m_target);
    }
    out[gid] = ans;
}

extern "C" void kernel_launch(void* const* d_in, const int* in_sizes, int n_in,
                              void* d_out, int out_size, void* d_ws, size_t ws_size,
                              hipStream_t stream) {
    (void)in_sizes; (void)n_in; (void)d_ws; (void)ws_size;
    const float* images = (const float*)d_in[0];
    float* out = (float*)d_out;
    // 4 batches * 4096 pixels = 16384 threads = 64 blocks x 256
    dtm_kernel<<<dim3(64), dim3(256), 0, stream>>>(images, out);
    (void)out_size;
}

// Round 2
// 84.037 us; speedup vs baseline: 1.2353x; 1.2353x over previous
//
#include <hip/hip_runtime.h>

// ExactWeightedDTM: B=4, C=1, H=W=64, N=4096, M0=0.01, R=2.0.
// R=2 => dists_pow == d2 (exact integer squared distance). Reference's
// sort+cumsum+clamp == accumulate mass in increasing d2 until
// m_target = 0.01*total; crossing group at distance T contributes
// (m_target - mass_below)*T (tie groups order-independent).
//
// R2 design: ONE WAVE PER PIXEL (R1 was one thread per pixel: 4% VALUBusy,
// latency-bound on serial dependent LDS reads). Each wave loads a 31x31
// window (padded to 32x32 enumeration, 16 (w,d2) pairs per lane) into
// REGISTERS, then binary-searches T with register-only F(t) evals +
// 6-step __shfl_xor butterfly reductions. If F(225) < m_target (window too
// small — probabilistically impossible for uniform(0,1) weights but required
// for correctness), a wave-uniform fallback scans the full LDS image.

#define NPIX 4096
#define D2MAX 7938   // 63^2 + 63^2

static __device__ __forceinline__ float wave_reduce_add(float s) {
#pragma unroll
    for (int m = 32; m >= 1; m >>= 1) s += __shfl_xor(s, m, 64);
    return s;
}

// Cold fallback: F(t) over the whole LDS image, cooperative across the wave.
static __device__ float mass_le_full(const float* __restrict__ img, int py, int px,
                                     int t, int lane) {
    float s = 0.f;
    for (int k = 0; k < 64; k++) {
        const int p  = lane + 64 * k;
        const int dy = (p >> 6) - py;
        const int dx = (p & 63) - px;
        const int d2 = dy * dy + dx * dx;
        s += (d2 <= t) ? img[p] : 0.f;
    }
    return wave_reduce_add(s);
}

__global__ __launch_bounds__(256) void dtm_kernel(const float* __restrict__ images,
                                                  float* __restrict__ out) {
    __shared__ float img[NPIX];
    __shared__ float red[256];

    const int tid  = threadIdx.x;
    const int lane = tid & 63;
    const int wave = tid >> 6;
    const int gpx  = blockIdx.x * 4 + wave;   // global pixel id (one wave each)
    const int b    = gpx >> 12;               // batch (4096 px/batch; 4 | 4096)
    const int pix  = gpx & (NPIX - 1);
    const int py   = pix >> 6;
    const int px   = pix & 63;

    // Stage this batch's image into LDS (float4) + block-reduce total mass.
    const float4* src = (const float4*)(images + b * NPIX);
    float4* dst = (float4*)img;
    float partial = 0.f;
#pragma unroll
    for (int i = 0; i < 4; i++) {
        float4 v = src[tid + 256 * i];
        dst[tid + 256 * i] = v;
        partial += v.x + v.y + v.z + v.w;
    }
    red[tid] = partial;
    __syncthreads();
    for (int s = 128; s > 0; s >>= 1) {
        if (tid < s) red[tid] += red[tid + s];
        __syncthreads();
    }
    const float total    = red[0];
    const float m_target = 0.01f * total;

    // Load 31x31 window around (py,px) into registers: slot j = lane + 64k,
    // wy=j>>5 in [0,31], wx=j&31 in [0,31]; dy=wy-15, dx=wx-15 in [-15,16];
    // mask dy==16 / dx==16 / out-of-image slots.
    float w[16];
    int   d2[16];
#pragma unroll
    for (int k = 0; k < 16; k++) {
        const int j  = lane + 64 * k;
        const int dy = (j >> 5) - 15;
        const int dx = (j & 31) - 15;
        const int y  = py + dy;
        const int x  = px + dx;
        const bool ok = (dy < 16) & (dx < 16) &
                        (y >= 0) & (y < 64) & (x >= 0) & (x < 64);
        const int addr = ok ? ((y << 6) + x) : 0;
        const float v = img[addr];
        w[k]  = ok ? v : 0.f;
        d2[k] = ok ? (dy * dy + dx * dx) : (1 << 30);
    }

    // Register-only F(t): predicated sum + butterfly reduce.
    auto F = [&](int t) -> float {
        float s = 0.f;
#pragma unroll
        for (int k = 0; k < 16; k++) s += (d2[k] <= t) ? w[k] : 0.f;
        return wave_reduce_add(s);
    };

    float ans = 0.f;
    if (total > 0.f) {
        int T;
        float mass_lt, wd;
        const float F225 = F(225);
        if (F225 >= m_target) {
            // Hot path: T <= 225, window provably contains all d2<=225 pixels.
            int lo = -1, hi = 225;
            while (hi - lo > 1) {
                const int mid = lo + ((hi - lo) >> 1);
                if (F(mid) >= m_target) hi = mid; else lo = mid;
            }
            T = hi;
            float ml = 0.f, wdl = 0.f;
#pragma unroll
            for (int k = 0; k < 16; k++) {
                if (d2[k] < T) { ml += w[k]; wdl += w[k] * (float)d2[k]; }
            }
            mass_lt = wave_reduce_add(ml);
            wd      = wave_reduce_add(wdl);
        } else {
            // Cold fallback: full-image cooperative search (wave-uniform).
            int lo = 225, hi = D2MAX;
            while (hi - lo > 1) {
                const int mid = lo + ((hi - lo) >> 1);
                if (mass_le_full(img, py, px, mid, lane) >= m_target) hi = mid;
                else lo = mid;
            }
            T = hi;
            float ml = 0.f, wdl = 0.f;
            for (int k = 0; k < 64; k++) {
                const int p  = lane + 64 * k;
                const int dy = (p >> 6) - py;
                const int dx = (p & 63) - px;
                const int dd = dy * dy + dx * dx;
                if (dd < T) { const float v = img[p]; ml += v; wdl += v * (float)dd; }
            }
            mass_lt = wave_reduce_add(ml);
            wd      = wave_reduce_add(wdl);
        }
        float rem = m_target - mass_lt;
        if (rem < 0.f) rem = 0.f;
        ans = sqrtf((wd + rem * (float)T) / m_target);
    }

    if (lane == 0) out[gpx] = ans;
}

extern "C" void kernel_launch(void* const* d_in, const int* in_sizes, int n_in,
                              void* d_out, int out_size, void* d_ws, size_t ws_size,
                              hipStream_t stream) {
    (void)in_sizes; (void)n_in; (void)d_ws; (void)ws_size; (void)out_size;
    const float* images = (const float*)d_in[0];
    float* out = (float*)d_out;
    // 16384 pixels, one wave each: 4096 blocks x 256 threads (4 waves/block).
    dtm_kernel<<<dim3(4096), dim3(256), 0, stream>>>(images, out);
}

// Round 4
// 58.506 us; speedup vs baseline: 1.7744x; 1.4364x over previous
//
#include <hip/hip_runtime.h>

// ExactWeightedDTM: B=4, C=1, H=W=64, N=4096, M0=0.01, R=2.0.
// R=2 => dists_pow == d2 (exact integer squared distance). The reference's
// sort/cumsum/clamp is EXACTLY a sequential scan in nondecreasing d2:
//   take = clamp(m_target - cum, 0, w);  wsum += take*d2;  cum += w;
// (tie groups are order-independent since they share the d2 multiplier).
//
// R4 = R3 with the constexpr UB fixed: pack offset with a +2048 bias so the
// shift operand is non-negative (<< of negative is not a constant expr).
//
// Design: one THREAD per pixel + compile-time d2-sorted offset table
// (radius 15, 709 entries — crossing needs ~41 px interior / ~165 px corner
// at m_target ~ 20.5). Block stages a ZERO-PADDED 94x96 image in LDS so the
// scan has no bounds checks: per element 1 stride-1 ds_read (conflict-free)
// + ~5 VALU, loads independent -> pipelined. Early exit via __all ballot in
// 16-element chunks. Exact full-image fallback (never runs) for correctness.
// R1 failed on serial dependent LDS chains; R2 on per-block redundant staging
// + shuffle-butterfly latency across 4096 blocks.

#define TABN 709
#define TABP 720            // padded to multiple of 16 (sentinel d2=255)
#define PSTRIDE 96          // padded row stride (floats), float4-friendly
#define PROWS 94            // rows -15..78
#define PFLOATS (PROWS * PSTRIDE)   // 9024 floats = 36 KB
#define OBIAS 2048          // offset bias so packed value is non-negative

struct Tab { int v[TABP]; };
static constexpr Tab make_tab() {
    Tab t{};
    int cnt[226] = {};
    for (int dy = -15; dy <= 15; dy++)
        for (int dx = -15; dx <= 15; dx++) {
            const int d2 = dy * dy + dx * dx;
            if (d2 <= 225) cnt[d2]++;
        }
    int pos[226] = {}; int run = 0;
    for (int d = 0; d < 226; d++) { pos[d] = run; run += cnt[d]; }
    for (int dy = -15; dy <= 15; dy++)
        for (int dx = -15; dx <= 15; dx++) {
            const int d2 = dy * dy + dx * dx;
            if (d2 <= 225)
                t.v[pos[d2]++] = ((dy * PSTRIDE + dx + OBIAS) << 8) | d2;
        }
    for (int i = TABN; i < TABP; i++) t.v[i] = (OBIAS << 8) | 255;  // sentinel
    return t;
}
__device__ constexpr Tab TAB = make_tab();

__global__ __launch_bounds__(256) void dtm_kernel(const float* __restrict__ images,
                                                  float* __restrict__ out) {
    __shared__ float pimg[PFLOATS];
    __shared__ float red4[4];

    const int tid = threadIdx.x;
    const int gid = blockIdx.x * 256 + tid;
    const int b   = gid >> 12;        // 4096 px/batch, 16 blocks/batch
    const int pix = gid & 4095;
    const int py  = pix >> 6;
    const int px  = pix & 63;

    // 1) zero the padded image (float4 stores; 9024/4 = 2256 vec4)
    float4* pv = (float4*)pimg;
#pragma unroll
    for (int i = 0; i < 9; i++) {
        const int idx = tid + 256 * i;
        if (idx < PFLOATS / 4) pv[idx] = make_float4(0.f, 0.f, 0.f, 0.f);
    }
    __syncthreads();

    // 2) copy interior rows (row y -> padded row y+15, col offset +16) and
    //    accumulate partial total mass.
    const float4* src = (const float4*)(images + (b << 12));
    float partial = 0.f;
#pragma unroll
    for (int i = 0; i < 4; i++) {
        const int fi = tid + 256 * i;     // float4 index 0..1023
        const int y  = fi >> 4;
        const int xq = fi & 15;
        const float4 v = src[fi];
        pv[(y + 15) * (PSTRIDE / 4) + 4 + xq] = v;  // ((y+15)*96+16)/4 + xq
        partial += v.x + v.y + v.z + v.w;
    }
    // wave reduce (6 shfl) + 4-slot LDS combine: only 2 barriers total.
#pragma unroll
    for (int m = 32; m >= 1; m >>= 1) partial += __shfl_xor(partial, m, 64);
    if ((tid & 63) == 0) red4[tid >> 6] = partial;
    __syncthreads();
    const float total    = red4[0] + red4[1] + red4[2] + red4[3];
    const float m_target = 0.01f * total;

    // 3) sequential scan in nondecreasing d2 over the precomputed table.
    const float* base = pimg + (py + 15) * PSTRIDE + (px + 16);
    float cum = 0.f, wd = 0.f;
    for (int c = 0; c < TABP; c += 16) {
#pragma unroll
        for (int i = 0; i < 16; i++) {
            const int v   = TAB.v[c + i];        // wave-uniform -> s_load
            const int off = (v >> 8) - OBIAS;    // dy*96+dx
            const int dv  = v & 255;
            float w = base[off];
            w = (dv <= 225) ? w : 0.f;           // sentinel kill
            const float take = fminf(fmaxf(m_target - cum, 0.f), w);
            wd  += take * (float)dv;
            cum += w;
        }
        if (__all(cum >= m_target)) break;
    }

    float ans = 0.f;
    if (total > 0.f) {
        if (cum < m_target) {
            // Exact fallback over the full image (never runs for this input):
            // binary-search min T with F(T) >= m_target, then strict-below sum.
            int lo = -1, hi = 7938;
            while (hi - lo > 1) {
                const int mid = lo + ((hi - lo) >> 1);
                float s = 0.f;
                for (int p = 0; p < 4096; p++) {
                    const int dy = (p >> 6) - py, dx = (p & 63) - px;
                    if (dy * dy + dx * dx <= mid)
                        s += pimg[((p >> 6) + 15) * PSTRIDE + (p & 63) + 16];
                }
                if (s >= m_target) hi = mid; else lo = mid;
            }
            const int T = hi;
            float ml = 0.f, wdl = 0.f;
            for (int p = 0; p < 4096; p++) {
                const int dy = (p >> 6) - py, dx = (p & 63) - px;
                const int dd = dy * dy + dx * dx;
                if (dd < T) {
                    const float wv = pimg[((p >> 6) + 15) * PSTRIDE + (p & 63) + 16];
                    ml += wv; wdl += wv * (float)dd;
                }
            }
            float rem = m_target - ml;
            if (rem < 0.f) rem = 0.f;
            wd = wdl + rem * (float)T;
        }
        ans = sqrtf(wd / m_target);
    }
    out[gid] = ans;
}

extern "C" void kernel_launch(void* const* d_in, const int* in_sizes, int n_in,
                              void* d_out, int out_size, void* d_ws, size_t ws_size,
                              hipStream_t stream) {
    (void)in_sizes; (void)n_in; (void)d_ws; (void)ws_size; (void)out_size;
    const float* images = (const float*)d_in[0];
    float* out = (float*)d_out;
    // 16384 pixels, one thread each: 64 blocks x 256 threads.
    dtm_kernel<<<dim3(64), dim3(256), 0, stream>>>(images, out);
}